// Round 1
// baseline (586.065 us; speedup 1.0000x reference)
//
#include <hip/hip_runtime.h>

#define B_ 64
#define T_ 512
#define D_ 1024
#define K_ 50

// ---------------------------------------------------------------------------
// Kernel 1: emissions GEMM, split-K=2.
// A[32768][1024] fp32, W[1024][50] fp32. Partial kh=0 -> d_out scores region,
// kh=1 -> workspace. grid (128, 2), 256 threads.
// Per-thread tile: 8 rows x 7 cols. BM=256, BK=16, b128 LDS reads (4k unroll).
// ---------------------------------------------------------------------------
#define BM 256
#define BK 16

__global__ __launch_bounds__(256) void gemm_kernel(const float* __restrict__ A,
                                                   const float* __restrict__ W,
                                                   float* __restrict__ P0,
                                                   float* __restrict__ P1) {
  __shared__ float As[BM][20];   // row stride 20 floats (80B, 16B-aligned)
  __shared__ float Wt[56][20];   // [c][k] transposed chunk

  const int tid = threadIdx.x;
  const int rowBase = blockIdx.x * BM;
  const int kh = blockIdx.y;
  const int kBase = kh * 512;
  float* __restrict__ P = kh ? P1 : P0;

  const int rg = tid & 31;        // row group 0..31
  const int cg = tid >> 5;        // col group 0..7 (7 cols each)

  float acc[8][7];
#pragma unroll
  for (int i = 0; i < 8; i++)
#pragma unroll
    for (int j = 0; j < 7; j++) acc[i][j] = 0.f;

  const int q = tid & 3;          // staging: col quad
  const int rr = tid >> 2;        // staging: row 0..63 (+64*s)

  for (int ch = 0; ch < 512 / BK; ++ch) {
    const int kb = kBase + ch * BK;
    // stage A tile (256 x 16)
#pragma unroll
    for (int s = 0; s < 4; s++) {
      const int r = rr + 64 * s;
      const float4 v = *(const float4*)&A[(size_t)(rowBase + r) * 1024 + kb + q * 4];
      *(float4*)&As[r][q * 4] = v;
    }
    // stage W^T chunk (16 x 50 -> [c][k]) : 800 contiguous floats
#pragma unroll
    for (int s = 0; s < 4; s++) {
      const int l = tid + 256 * s;
      if (l < 800) {
        const int kk = l / 50;
        const int c = l - kk * 50;
        Wt[c][kk] = W[(size_t)(kb + kk) * 50 + c];
      }
    }
    __syncthreads();
#pragma unroll
    for (int k4 = 0; k4 < BK; k4 += 4) {
      float4 a[8];
#pragma unroll
      for (int i = 0; i < 8; i++) a[i] = *(const float4*)&As[rg + 32 * i][k4];
#pragma unroll
      for (int j = 0; j < 7; j++) {
        const float4 w = *(const float4*)&Wt[cg * 7 + j][k4];
#pragma unroll
        for (int i = 0; i < 8; i++) {
          acc[i][j] += a[i].x * w.x + a[i].y * w.y + a[i].z * w.z + a[i].w * w.w;
        }
      }
    }
    __syncthreads();
  }
#pragma unroll
  for (int i = 0; i < 8; i++) {
    const int row = rowBase + rg + 32 * i;
#pragma unroll
    for (int j = 0; j < 7; j++) {
      const int c = cg * 7 + j;
      if (c < 50) P[(size_t)row * 50 + c] = acc[i][j];
    }
  }
}

// ---------------------------------------------------------------------------
// Kernel 2: combine split-K partials + bias + mask -> scores (in d_out).
// Also zeroes the loss slot (stream-ordered before CRF kernel's atomics).
// grid 6400 x 256 covers 32768*50 exactly.
// ---------------------------------------------------------------------------
__global__ __launch_bounds__(256) void combine_kernel(const float* __restrict__ P0,
                                                      const float* __restrict__ P1,
                                                      const float* __restrict__ bias,
                                                      const int* __restrict__ mask,
                                                      float* __restrict__ scores,
                                                      float* __restrict__ lossSlot) {
  const int idx = blockIdx.x * 256 + threadIdx.x;
  const int m = idx / 50;
  const int c = idx - m * 50;
  float v = P0[idx] + P1[idx] + bias[c];
  v *= (float)mask[m];
  scores[idx] = v;
  if (idx == 0) *lossSlot = 0.f;
}

// ---------------------------------------------------------------------------
// Kernel 3: CRF recurrences. grid (64, 2): y==0 forward/logZ/gold/loss,
// y==1 Viterbi + chunked backtrace. 256 threads = 4 waves, j-split
// {12,12,12,14} (16B-aligned ranges). One __syncthreads per step
// (double-buffered partials). Viterbi is bit-exact vs reference given
// identical emissions (order-independent max, first-index tie-break).
// ---------------------------------------------------------------------------
__global__ __launch_bounds__(256) void crf_kernel(const float* __restrict__ scores,
                                                  const int* __restrict__ mask,
                                                  const int* __restrict__ labels,
                                                  const float* __restrict__ trans,
                                                  const float* __restrict__ startT,
                                                  const float* __restrict__ endT,
                                                  float* __restrict__ tagsOut,
                                                  float* __restrict__ lossSlot) {
  __shared__ float e_lds[64];
  __shared__ float ps_lds[2][4][64];
  __shared__ float av_lds[64];
  __shared__ float pv_lds[2][4][64];
  __shared__ int pj_lds[2][4][64];
  __shared__ unsigned char bp_s[511 * 52];
  __shared__ unsigned char g_s[32 * 52];
  __shared__ unsigned char chin_s[32];
  __shared__ float redp_s[4];
  __shared__ int redm_s[4];

  const int b = blockIdx.x;
  const int tid = threadIdx.x;
  const int wave = tid >> 6;
  const int lane = tid & 63;
  const int k = lane;
  const int kc = (k < 50) ? k : 49;

  const int j0s[4] = {0, 12, 24, 36};
  const int jns[4] = {12, 12, 12, 14};
  const int j0 = j0s[wave];
  const int jn = jns[wave];

  if (tid < 64) { e_lds[tid] = 0.f; av_lds[tid] = 0.f; }
  __syncthreads();

  const size_t sb = (size_t)b * T_ * 50;

  if (blockIdx.y == 0) {
    // ---------------- forward (log-partition) ----------------
    float eT[14];
#pragma unroll
    for (int jj = 0; jj < 14; jj++) {
      const int j = j0 + jj;
      eT[jj] = (jj < jn) ? __expf(trans[j * 50 + kc]) : 0.f;
    }
    float af = (k < 50) ? (startT[k] + scores[sb + k]) : -1e30f;
    float M = __int_as_float(__builtin_amdgcn_readfirstlane(__float_as_int(af)));
    float emit_next = scores[sb + 50 + kc];
    int mnext = mask[b * T_ + 1];
    int buf = 0;
    for (int t = 1; t < T_; ++t) {
      const float emit = emit_next;
      const int mt = mnext;
      if (t < T_ - 1) {
        emit_next = scores[sb + (size_t)(t + 1) * 50 + kc];
        mnext = mask[b * T_ + t + 1];
      }
      const float e = __expf(af - M);
      if (lane >= j0 && lane < j0 + jn) e_lds[lane] = e;
      float ev[16];
#pragma unroll
      for (int u = 0; u < 4; u++) *(float4*)&ev[4 * u] = *(const float4*)&e_lds[j0 + 4 * u];
      float ps = 0.f;
#pragma unroll
      for (int jj = 0; jj < 14; jj++) ps += ev[jj] * eT[jj];
      ps_lds[buf][wave][lane] = ps;
      __syncthreads();
      const float S = (ps_lds[buf][0][lane] + ps_lds[buf][1][lane]) +
                      (ps_lds[buf][2][lane] + ps_lds[buf][3][lane]);
      const float afn = M + __logf(S) + emit;
      af = (mt > 0) ? afn : af;
      M = __int_as_float(__builtin_amdgcn_readfirstlane(__float_as_int(af)));
      buf ^= 1;
    }
    // logZ = LSE(af + end)
    const float x = (k < 50) ? (af + endT[k]) : -3e38f;
    float mx = x;
#pragma unroll
    for (int off = 32; off >= 1; off >>= 1) mx = fmaxf(mx, __shfl_xor(mx, off));
    float sm = (k < 50) ? __expf(x - mx) : 0.f;
#pragma unroll
    for (int off = 32; off >= 1; off >>= 1) sm += __shfl_xor(sm, off);
    const float logZ = mx + __logf(sm);
    // gold score partials
    float part = 0.f;
    int mcnt = 0;
#pragma unroll
    for (int s2 = 0; s2 < 2; s2++) {
      const int t = tid + 256 * s2;
      const int lt = labels[b * T_ + t];
      const int mt = mask[b * T_ + t];
      mcnt += mt;
      part += (mt > 0) ? scores[sb + (size_t)t * 50 + lt] : 0.f;
      if (t < T_ - 1) {
        const int ln = labels[b * T_ + t + 1];
        const int mn = mask[b * T_ + t + 1];
        part += (mn > 0) ? trans[lt * 50 + ln] : 0.f;
      }
    }
#pragma unroll
    for (int off = 32; off >= 1; off >>= 1) {
      part += __shfl_xor(part, off);
      mcnt += __shfl_xor(mcnt, off);
    }
    if (lane == 0) { redp_s[wave] = part; redm_s[wave] = mcnt; }
    __syncthreads();
    if (tid == 0) {
      float gold = redp_s[0] + redp_s[1] + redp_s[2] + redp_s[3];
      const int tot = redm_s[0] + redm_s[1] + redm_s[2] + redm_s[3];
      const int l0 = labels[b * T_];
      const int llast = labels[b * T_ + (tot - 1)];
      gold += startT[l0] + endT[llast];
      atomicAdd(lossSlot, -(gold - logZ));
    }
  } else {
    // ---------------- Viterbi ----------------
    float Tv[14];
#pragma unroll
    for (int jj = 0; jj < 14; jj++) {
      const int j = j0 + jj;
      Tv[jj] = (jj < jn) ? trans[j * 50 + kc] : -1e30f;
    }
    float av = (k < 50) ? (startT[k] + scores[sb + k]) : -1e30f;
    float emit_next = scores[sb + 50 + kc];
    int mnext = mask[b * T_ + 1];
    int buf = 0;
    for (int t = 1; t < T_; ++t) {
      const float emit = emit_next;
      const int mt = mnext;
      if (t < T_ - 1) {
        emit_next = scores[sb + (size_t)(t + 1) * 50 + kc];
        mnext = mask[b * T_ + t + 1];
      }
      if (lane >= j0 && lane < j0 + jn) av_lds[lane] = av;
      float avv[16];
#pragma unroll
      for (int u = 0; u < 4; u++) *(float4*)&avv[4 * u] = *(const float4*)&av_lds[j0 + 4 * u];
      float best = -3e38f;
      int bj = 0;
#pragma unroll
      for (int jj = 0; jj < 14; jj++) {
        const float u = avv[jj] + Tv[jj];
        if (u > best) { best = u; bj = jj; }
      }
      pv_lds[buf][wave][lane] = best;
      pj_lds[buf][wave][lane] = j0 + bj;
      __syncthreads();
      float bv = pv_lds[buf][0][lane];
      int bi = pj_lds[buf][0][lane];
#pragma unroll
      for (int w = 1; w < 4; w++) {
        const float v2 = pv_lds[buf][w][lane];
        const int i2 = pj_lds[buf][w][lane];
        if (v2 > bv) { bv = v2; bi = i2; }
      }
      const bool upd = mt > 0;
      if (wave == 0 && k < 50) bp_s[(t - 1) * 52 + k] = (unsigned char)(upd ? bi : k);
      av = upd ? (bv + emit) : av;
      buf ^= 1;
    }
    // final argmax (first-index tie-break)
    float x = (k < 50) ? (av + endT[k]) : -3e38f;
    int xi = (k < 50) ? k : 63;
#pragma unroll
    for (int off = 32; off >= 1; off >>= 1) {
      const float ov = __shfl_xor(x, off);
      const int oi = __shfl_xor(xi, off);
      if (ov > x || (ov == x && oi < xi)) { x = ov; xi = oi; }
    }
    const int last = xi;
    __syncthreads();  // bp_s complete
    // phase A: compose 16-step chunks g_c(s)
    for (int p = 0; p < 7; p++) {
      const int idx = tid + 256 * p;
      if (idx < 1600) {
        const int c = idx / 50;
        const int s2 = idx - c * 50;
        int x2 = s2;
        const int lo = 16 * c;
        const int hi = min(16 * c + 15, 510);
        for (int i = hi; i >= lo; --i) x2 = bp_s[i * 52 + x2];
        g_s[c * 52 + s2] = (unsigned char)x2;
      }
    }
    __syncthreads();
    // phase B: serial chunk-boundary walk (32 steps)
    if (tid == 0) {
      int cur = last;
      chin_s[31] = (unsigned char)cur;
      for (int c = 31; c >= 1; --c) {
        cur = g_s[c * 52 + cur];
        chin_s[c - 1] = (unsigned char)cur;
      }
      const int m511 = mask[b * T_ + 511];
      tagsOut[(size_t)b * T_ + 511] = (float)((m511 > 0) ? last : 0);
    }
    __syncthreads();
    // phase C: per-chunk backtrace + tag stores
    if (tid < 32) {
      const int c = tid;
      int x3 = chin_s[c];
      const int lo = 16 * c;
      const int hi = min(16 * c + 15, 510);
      for (int i = hi; i >= lo; --i) {
        x3 = bp_s[i * 52 + x3];
        const int mi = mask[b * T_ + i];
        tagsOut[(size_t)b * T_ + i] = (float)((mi > 0) ? x3 : 0);
      }
    }
  }
}

// ---------------------------------------------------------------------------
extern "C" void kernel_launch(void* const* d_in, const int* in_sizes, int n_in,
                              void* d_out, int out_size, void* d_ws, size_t ws_size,
                              hipStream_t stream) {
  const float* inputs = (const float*)d_in[0];
  const int* mask = (const int*)d_in[1];
  const int* labels = (const int*)d_in[2];
  const float* W = (const float*)d_in[3];
  const float* bias = (const float*)d_in[4];
  const float* trans = (const float*)d_in[5];
  const float* startT = (const float*)d_in[6];
  const float* endT = (const float*)d_in[7];

  float* out = (float*)d_out;
  float* scores = out;                                  // 64*512*50
  float* tagsOut = out + (size_t)B_ * T_ * K_;          // 64*512
  float* lossSlot = out + (size_t)B_ * T_ * K_ + B_ * T_;
  float* P1 = (float*)d_ws;                             // 6.55 MB partial

  dim3 g1(128, 2);
  gemm_kernel<<<g1, 256, 0, stream>>>(inputs, W, scores, P1);

  combine_kernel<<<(B_ * T_ * K_) / 256, 256, 0, stream>>>(scores, P1, bias, mask,
                                                           scores, lossSlot);

  dim3 g3(B_, 2);
  crf_kernel<<<g3, 256, 0, stream>>>(scores, mask, labels, trans, startT, endT,
                                     tagsOut, lossSlot);
}